// Round 8
// baseline (952.192 us; speedup 1.0000x reference)
//
#include <hip/hip_runtime.h>
#include <hip/hip_bf16.h>
#include <math.h>

#define B_ 2
#define T_ 512
#define N_ 512
#define H_ 64
#define NBLK 1024u
#define GRP 32
#define GSZ (NBLK / GRP)          // 32 blocks per arrival group
#define BAR_STRIDE 8192           // uints per barrier region (32 KB); max idx 4096 < 8192

typedef __attribute__((ext_vector_type(8))) short short8;
typedef __attribute__((ext_vector_type(4))) float floatx4;

__device__ inline short f2bf(float f) {
    union { float f; unsigned u; } v; v.f = f;
    unsigned r = (v.u + 0x7fffu + ((v.u >> 16) & 1u)) >> 16;  // RNE
    return (short)r;
}

// Hierarchical software grid barrier (R7 bug fixed: region was 4096 uints but
// flag g=31 sits at (1+32+31)*64 = 4096 -> overflowed into next region /
// unpoisoned ws. Now BAR_STRIDE=8192.)
// SAFETY: __launch_bounds__(256,4) + VGPR<=128 (R6 measured 104) -> 4
// blocks/CU capacity -> 1024 blocks <= 1024 slots -> all resident (R6-proven
// greedy-dispatch argument). Arrivals: 32 group counters (32 RMWs each) +
// 32-RMW root; release: 32 padded flag lines, <=32 pollers/line, s_sleep
// backoff (single-line design collapsed at ~40us/barrier in R6).
// Layout (uints): [0]=root, [(1+g)*64]=grp cnt g, [(1+GRP+g)*64]=flag g.
__device__ inline void gbar(unsigned* base, int blk) {
    __syncthreads();
    if (threadIdx.x == 0) {
        __threadfence();                                   // release my writes
        int g = blk & (GRP - 1);
        unsigned* grp  = base + (1 + g) * 64;
        unsigned* flag = base + (1 + GRP + g) * 64;
        unsigned old = atomicAdd(grp, 1u);                 // device scope
        if (old == GSZ - 1) {
            unsigned r = atomicAdd(base, 1u);              // root
            if (r == GRP - 1) {
                for (int k = 0; k < GRP; k++)
                    __hip_atomic_store(base + (1 + GRP + k) * 64, 1u,
                                       __ATOMIC_RELEASE, __HIP_MEMORY_SCOPE_AGENT);
            }
        }
        while (__hip_atomic_load(flag, __ATOMIC_ACQUIRE, __HIP_MEMORY_SCOPE_AGENT) == 0u)
            __builtin_amdgcn_s_sleep(8);
        __threadfence();                                   // acquire remote writes
    }
    __syncthreads();
}

// ---------------------------------------------------------------------------
// Single fused kernel, 1024 blocks x 256 threads (4 blocks/CU), software
// barriers between phases:
// P1: dyn partials (blk<512) + prior table (all) + W3 pack (blk>=512)
// P2: node MLP, one (b,n) per block (wave 0) -> nr, P, Qp
// P3: pairwise MFMA, one (b,i) per block -> adapt, deg
// P4: symmetric normalization -> out
// ---------------------------------------------------------------------------
__global__ __launch_bounds__(256, 4) void fused_kernel(
        const float* __restrict__ x, const float* __restrict__ mask,
        const float* __restrict__ sc, const float* __restrict__ coords,
        const float* __restrict__ W1, const float* __restrict__ b1,
        const float* __restrict__ W2, const float* __restrict__ b2,
        const float* __restrict__ W3, const float* __restrict__ b3,
        const float* __restrict__ W4, const float* __restrict__ b4,
        float* __restrict__ part, float* __restrict__ prior,
        short* __restrict__ W3p, float* __restrict__ nr,
        float* __restrict__ P, float* __restrict__ Qp,
        float* __restrict__ adapt, float* __restrict__ deg,
        float* __restrict__ out, unsigned* __restrict__ bar) {
    int blk = blockIdx.x;
    int tid = threadIdx.x;

    __shared__ float red[6][4][64];
    __shared__ float sRow[4];

    // ================= Phase 1: prep =================
    {
        if (blk < 512) {
            // dyn partials: 256 thr = 64 n x 4 tt, 16 t-steps per block
            int b  = blk >> 8;
            int nc = (blk >> 5) & 7;
            int tc = blk & 31;
            int tn = tid & 63;
            int tt = tid >> 6;
            int n  = nc * 64 + tn;

            float sx = 0.f, sxx = 0.f, cnt = 0.f, msum = 0.f, bv = 0.f, bt = -1.f;
#pragma unroll
            for (int it = 0; it < 4; it++) {
                int t = tc * 16 + it * 4 + tt;
                int off = (b * T_ + t) * N_ + n;
                float xv = x[off];
                float mv = mask[off];
                float obs = 1.f - mv;
                sx   += xv * obs;
                sxx  += xv * xv * obs;
                cnt  += obs;
                msum += mv;
                if (obs > 0.5f) { bt = (float)t; bv = xv; }
            }
            red[0][tt][tn] = sx;  red[1][tt][tn] = sxx; red[2][tt][tn] = cnt;
            red[3][tt][tn] = msum; red[4][tt][tn] = bv; red[5][tt][tn] = bt;
            __syncthreads();
            if (tid < 64) {
                float Sx = 0.f, Sxx = 0.f, Cnt = 0.f, Ms = 0.f, Bv = 0.f, Bt = -1.f;
#pragma unroll
                for (int u = 0; u < 4; u++) {
                    Sx  += red[0][u][tn];
                    Sxx += red[1][u][tn];
                    Cnt += red[2][u][tn];
                    Ms  += red[3][u][tn];
                    float btu = red[5][u][tn];
                    if (btu > Bt) { Bt = btu; Bv = red[4][u][tn]; }
                }
                const int plane = B_ * 32 * N_;
                int base = (b * 32 + tc) * N_ + n;
                part[0 * plane + base] = Sx;
                part[1 * plane + base] = Sxx;
                part[2 * plane + base] = Cnt;
                part[3 * plane + base] = Ms;
                part[4 * plane + base] = Bv;
                part[5 * plane + base] = Bt;
            }
        } else {
            // W3cd pack (fragment order): 16 entries per block, blocks 512..1023
            if (tid < 16) {
                int k = (blk - 512) * 16 + tid;
                int t = k & 7;
                int l = (k >> 3) & 63;
                int f = k >> 9;
                int s = f >> 2, nt = f & 3;
                int quad = l >> 4, col = l & 15;
                W3p[k] = f2bf(W3[(128 + s * 32 + quad * 8 + t) * H_ + nt * 16 + col]);
            }
        }

        // prior table: 256 entries per block, all 1024 blocks
        {
            int idx = blk * 256 + tid;
            int pi = idx >> 9, pj = idx & (N_ - 1);
            float d2 = 0.f;
#pragma unroll
            for (int c = 0; c < 8; c++) {
                float df = coords[pi * 8 + c] - coords[pj * 8 + c];
                d2 += df * df;
            }
            float dist = (d2 > 0.f) ? sqrtf(d2) : 0.f;
            prior[idx] = (pi == pj) ? 0.f : 1.f / (1.f + dist);
        }
    }
    gbar(bar + 0 * BAR_STRIDE, blk);

    // ================= Phase 2: node MLP (wave 0, one (b,n) per block) =====
    {
        int o = tid & 63;
        if (tid < 64) {
            int b = blk >> 9;
            int n = blk & (N_ - 1);
            const int plane = B_ * 32 * N_;
            int base = (b * 32 + (o & 31)) * N_ + n;
            float Sx  = part[0 * plane + base];
            float Sxx = part[1 * plane + base];
            float Cnt = part[2 * plane + base];
            float Ms  = part[3 * plane + base];
            float Bv  = part[4 * plane + base];
            float Bt  = part[5 * plane + base];
#pragma unroll
            for (int off = 1; off < 32; off <<= 1) {
                Sx  += __shfl_xor(Sx, off);
                Sxx += __shfl_xor(Sxx, off);
                Cnt += __shfl_xor(Cnt, off);
                Ms  += __shfl_xor(Ms, off);
                float obt = __shfl_xor(Bt, off);
                float obv = __shfl_xor(Bv, off);
                if (obt > Bt) { Bt = obt; Bv = obv; }
            }
            float count = fmaxf(Cnt, 1.f);
            float mean  = Sx / count;
            float var   = (Sxx - 2.f * mean * Sx + mean * mean * Cnt) / count;
            float stdv  = sqrtf(fmaxf(var, 0.f) + 1e-6f);
            float last  = (Bt >= 0.f) ? Bv : x[b * T_ * N_ + n];
            float mr    = Ms * (1.f / (float)T_);

            float a = b1[o] + mean * W1[o] + stdv * W1[H_ + o] +
                      last * W1[2 * H_ + o] + mr * W1[3 * H_ + o];
#pragma unroll
            for (int c = 0; c < 8; c++)
                a += sc[n * 8 + c] * W1[(4 + c) * H_ + o];
            float h = fmaxf(a, 0.f);

            float a2 = b2[o];
#pragma unroll 16
            for (int k = 0; k < H_; k++)
                a2 += __shfl(h, k) * W2[k * H_ + o];
            float rv = fmaxf(a2, 0.f);
            nr[(b * N_ + n) * H_ + o] = rv;

            float p = 0.f, q = 0.f;
#pragma unroll 16
            for (int k = 0; k < H_; k++) {
                float rk = __shfl(rv, k);
                p += rk * W3[k * H_ + o];
                q += rk * W3[(H_ + k) * H_ + o];
            }
            P[(b * N_ + n) * H_ + o] = p;
            Qp[(b * N_ + n) * H_ + (o & 15) * 4 + (o >> 4)] = q;
        }
    }
    gbar(bar + 1 * BAR_STRIDE, blk);

    // ================= Phase 3: pairwise MFMA, one (b,i) per block ========
    {
        int rb = blk >> 9;
        int i  = blk & (N_ - 1);
        int w = tid >> 6;
        int l = tid & 63;
        int col = l & 15;
        int quad = l >> 4;

        short8 bf[4][4];
#pragma unroll
        for (int s = 0; s < 4; s++)
#pragma unroll
            for (int nt = 0; nt < 4; nt++)
                bf[s][nt] = *(const short8*)(W3p + (((s * 4 + nt) * 64 + l) << 3));

        float w4v[4];
#pragma unroll
        for (int nt = 0; nt < 4; nt++) w4v[nt] = W4[nt * 16 + col];
        float b4s = b4[0];
        const float* prow = prior + i * N_;

        const float* hi_row = nr + (rb * N_ + i) * H_;
        floatx4 hiA0 = *(const floatx4*)(hi_row + quad * 8);
        floatx4 hiA1 = *(const floatx4*)(hi_row + quad * 8 + 4);
        floatx4 hiB0 = *(const floatx4*)(hi_row + 32 + quad * 8);
        floatx4 hiB1 = *(const floatx4*)(hi_row + 32 + quad * 8 + 4);

        float pb3[4];
#pragma unroll
        for (int nt = 0; nt < 4; nt++) {
            int o = nt * 16 + col;
            pb3[nt] = P[(rb * N_ + i) * H_ + o] + b3[o];
        }
        const float* nrb = nr + (rb * N_) * H_;
        float rsum = 0.f;

        floatx4 hA0, hA1, hB0, hB1;
        {
            const float* p0 = nrb + (w * 128 + col) * H_;
            hA0 = *(const floatx4*)(p0 + quad * 8);
            hA1 = *(const floatx4*)(p0 + quad * 8 + 4);
            hB0 = *(const floatx4*)(p0 + 32 + quad * 8);
            hB1 = *(const floatx4*)(p0 + 32 + quad * 8 + 4);
        }

#pragma unroll
        for (int mt = 0; mt < 8; mt++) {
            int j0 = w * 128 + mt * 16;

            floatx4 nA0, nA1, nB0, nB1;
            if (mt < 7) {
                const float* pn = nrb + (j0 + 16 + col) * H_;
                nA0 = *(const floatx4*)(pn + quad * 8);
                nA1 = *(const floatx4*)(pn + quad * 8 + 4);
                nB0 = *(const floatx4*)(pn + 32 + quad * 8);
                nB1 = *(const floatx4*)(pn + 32 + quad * 8 + 4);
            }

            floatx4 pv = *(const floatx4*)(prow + j0 + quad * 4);
            floatx4 qv[4];
#pragma unroll
            for (int r = 0; r < 4; r++)
                qv[r] = *(const floatx4*)(Qp + (rb * N_ + j0 + quad * 4 + r) * H_ + col * 4);

            union { short8 s; __hip_bfloat162 h[4]; } a0, a1, a2, a3;
#pragma unroll
            for (int t = 0; t < 2; t++) {
                a0.h[t]     = __float22bfloat162_rn(make_float2(fabsf(hiA0[2*t] - hA0[2*t]),
                                                                fabsf(hiA0[2*t+1] - hA0[2*t+1])));
                a0.h[t + 2] = __float22bfloat162_rn(make_float2(fabsf(hiA1[2*t] - hA1[2*t]),
                                                                fabsf(hiA1[2*t+1] - hA1[2*t+1])));
                a1.h[t]     = __float22bfloat162_rn(make_float2(fabsf(hiB0[2*t] - hB0[2*t]),
                                                                fabsf(hiB0[2*t+1] - hB0[2*t+1])));
                a1.h[t + 2] = __float22bfloat162_rn(make_float2(fabsf(hiB1[2*t] - hB1[2*t]),
                                                                fabsf(hiB1[2*t+1] - hB1[2*t+1])));
                a2.h[t]     = __float22bfloat162_rn(make_float2(hiA0[2*t] * hA0[2*t],
                                                                hiA0[2*t+1] * hA0[2*t+1]));
                a2.h[t + 2] = __float22bfloat162_rn(make_float2(hiA1[2*t] * hA1[2*t],
                                                                hiA1[2*t+1] * hA1[2*t+1]));
                a3.h[t]     = __float22bfloat162_rn(make_float2(hiB0[2*t] * hB0[2*t],
                                                                hiB0[2*t+1] * hB0[2*t+1]));
                a3.h[t + 2] = __float22bfloat162_rn(make_float2(hiB1[2*t] * hB1[2*t],
                                                                hiB1[2*t+1] * hB1[2*t+1]));
            }

            floatx4 acc[4];
#pragma unroll
            for (int nt = 0; nt < 4; nt++) acc[nt] = (floatx4){0.f, 0.f, 0.f, 0.f};
#pragma unroll
            for (int nt = 0; nt < 4; nt++) {
                acc[nt] = __builtin_amdgcn_mfma_f32_16x16x32_bf16(a0.s, bf[0][nt], acc[nt], 0, 0, 0);
                acc[nt] = __builtin_amdgcn_mfma_f32_16x16x32_bf16(a1.s, bf[1][nt], acc[nt], 0, 0, 0);
                acc[nt] = __builtin_amdgcn_mfma_f32_16x16x32_bf16(a2.s, bf[2][nt], acc[nt], 0, 0, 0);
                acc[nt] = __builtin_amdgcn_mfma_f32_16x16x32_bf16(a3.s, bf[3][nt], acc[nt], 0, 0, 0);
            }

            float ed[4];
#pragma unroll
            for (int r = 0; r < 4; r++) {
                int j = j0 + quad * 4 + r;
                float p = 0.f;
#pragma unroll
                for (int nt = 0; nt < 4; nt++)
                    p += fmaxf(acc[nt][r] + pb3[nt] + qv[r][nt], 0.f) * w4v[nt];
                p += __shfl_xor(p, 1);
                p += __shfl_xor(p, 2);
                p += __shfl_xor(p, 4);
                p += __shfl_xor(p, 8);
                float edge = fmaxf(p + b4s, 0.f);
                float ad = (j == i) ? 1.0f : edge * pv[r];
                ed[r] = ad;
                rsum += ad;
            }
            if (col == 0) {
                *(floatx4*)&adapt[(size_t)(rb * N_ + i) * N_ + j0 + quad * 4] =
                    (floatx4){ed[0], ed[1], ed[2], ed[3]};
            }
            if (mt < 7) { hA0 = nA0; hA1 = nA1; hB0 = nB0; hB1 = nB1; }
        }

        rsum += __shfl_xor(rsum, 16);
        rsum += __shfl_xor(rsum, 32);
        if (l == 0) sRow[w] = rsum;
        __syncthreads();
        if (tid == 0)
            deg[rb * N_ + i] = sRow[0] + sRow[1] + sRow[2] + sRow[3];
    }
    gbar(bar + 2 * BAR_STRIDE, blk);

    // ================= Phase 4: normalization =================
    {
        if (tid < 128) {
            int fid = blk * 128 + tid;             // float4 index, 131072 total
            int b = fid >> 16;
            int r = (fid >> 7) & (N_ - 1);
            int c4 = (fid & 127) << 2;
            float dr = rsqrtf(fmaxf(deg[b * N_ + r], 1e-6f));
            floatx4 a = *(const floatx4*)(adapt + ((size_t)fid << 2));
            floatx4 o;
#pragma unroll
            for (int k = 0; k < 4; k++)
                o[k] = dr * a[k] * rsqrtf(fmaxf(deg[b * N_ + c4 + k], 1e-6f));
            *(floatx4*)(out + ((size_t)fid << 2)) = o;
        }
    }
}

extern "C" void kernel_launch(void* const* d_in, const int* in_sizes, int n_in,
                              void* d_out, int out_size, void* d_ws, size_t ws_size,
                              hipStream_t stream) {
    const float* x      = (const float*)d_in[0];
    const float* mask   = (const float*)d_in[1];
    const float* sc     = (const float*)d_in[2];
    const float* coords = (const float*)d_in[3];
    const float* W1 = (const float*)d_in[4];
    const float* b1 = (const float*)d_in[5];
    const float* W2 = (const float*)d_in[6];
    const float* b2 = (const float*)d_in[7];
    const float* W3 = (const float*)d_in[8];
    const float* b3 = (const float*)d_in[9];
    const float* W4 = (const float*)d_in[10];
    const float* b4 = (const float*)d_in[11];
    float* out = (float*)d_out;

    float* wsp = (float*)d_ws;
    float* nr    = wsp;                      // 65536
    float* P     = wsp + 65536;              // 65536
    float* Qp    = wsp + 131072;             // 65536
    float* prior = wsp + 196608;             // 262144
    short* W3p   = (short*)(wsp + 458752);   // 8192 shorts (4096 floats)
    float* deg   = wsp + 462848;             // 1024
    float* adapt = wsp + 463872;             // 524288; dyn partials overlay
    float* part  = adapt;                    // 6*B*32*N = 196608 <= 524288
    unsigned* bar = (unsigned*)(wsp + 1048576); // 3 x BAR_STRIDE uints = 96 KB

    hipMemsetAsync((void*)bar, 0, 3 * BAR_STRIDE * sizeof(unsigned), stream);

    fused_kernel<<<NBLK, 256, 0, stream>>>(
        x, mask, sc, coords, W1, b1, W2, b2, W3, b3, W4, b4,
        part, prior, W3p, nr, P, Qp, adapt, deg, out, bar);
}

// Round 9
// 113.274 us; speedup vs baseline: 8.4061x; 8.4061x over previous
//
#include <hip/hip_runtime.h>
#include <math.h>

#define B_ 2
#define T_ 512
#define N_ 512
#define H_ 64

typedef _Float16 half8 __attribute__((ext_vector_type(8)));
typedef __attribute__((ext_vector_type(4))) float floatx4;

__device__ inline half8 habs8(half8 v) {
    union { half8 h; unsigned u[4]; } x; x.h = v;
    x.u[0] &= 0x7fff7fffu; x.u[1] &= 0x7fff7fffu;
    x.u[2] &= 0x7fff7fffu; x.u[3] &= 0x7fff7fffu;
    return x.h;
}

// ---------------------------------------------------------------------------
// Kernel 1 (fused prep): grid-partitioned independent work.
//   blocks 0..511     : dyn partials (B*8 n-chunks x 32 t-chunks)
//   blocks 512..1535  : prior adjacency table (512x512)
//   blocks 1536..1567 : W3[128:256] f16 pack in MFMA fragment order
// ---------------------------------------------------------------------------
__global__ void prep_kernel(const float* __restrict__ x, const float* __restrict__ mask,
                            const float* __restrict__ coords, const float* __restrict__ W3,
                            float* __restrict__ part, float* __restrict__ prior,
                            _Float16* __restrict__ W3ph) {
    int blk = blockIdx.x;
    if (blk < 512) {
        int b  = blk >> 8;
        int nc = (blk >> 5) & 7;
        int tc = blk & 31;
        int tn = threadIdx.x & 63;
        int tt = threadIdx.x >> 6;
        int n  = nc * 64 + tn;

        float sx = 0.f, sxx = 0.f, cnt = 0.f, msum = 0.f, bv = 0.f, bt = -1.f;
#pragma unroll
        for (int it = 0; it < 4; it++) {
            int t = tc * 16 + it * 4 + tt;
            int off = (b * T_ + t) * N_ + n;
            float xv = x[off];
            float mv = mask[off];
            float obs = 1.f - mv;
            sx   += xv * obs;
            sxx  += xv * xv * obs;
            cnt  += obs;
            msum += mv;
            if (obs > 0.5f) { bt = (float)t; bv = xv; }
        }

        __shared__ float red[6][4][64];
        red[0][tt][tn] = sx;  red[1][tt][tn] = sxx; red[2][tt][tn] = cnt;
        red[3][tt][tn] = msum; red[4][tt][tn] = bv; red[5][tt][tn] = bt;
        __syncthreads();

        if (threadIdx.x < 64) {
            float Sx = 0.f, Sxx = 0.f, Cnt = 0.f, Ms = 0.f, Bv = 0.f, Bt = -1.f;
#pragma unroll
            for (int u = 0; u < 4; u++) {
                Sx  += red[0][u][tn];
                Sxx += red[1][u][tn];
                Cnt += red[2][u][tn];
                Ms  += red[3][u][tn];
                float btu = red[5][u][tn];
                if (btu > Bt) { Bt = btu; Bv = red[4][u][tn]; }
            }
            const int plane = B_ * 32 * N_;
            int base = (b * 32 + tc) * N_ + n;
            part[0 * plane + base] = Sx;
            part[1 * plane + base] = Sxx;
            part[2 * plane + base] = Cnt;
            part[3 * plane + base] = Ms;
            part[4 * plane + base] = Bv;
            part[5 * plane + base] = Bt;
        }
    } else if (blk < 1536) {
        int idx = (blk - 512) * 256 + threadIdx.x;
        int i = idx >> 9, j = idx & (N_ - 1);
        float d2 = 0.f;
#pragma unroll
        for (int c = 0; c < 8; c++) {
            float df = coords[i * 8 + c] - coords[j * 8 + c];
            d2 += df * df;
        }
        float dist = (d2 > 0.f) ? sqrtf(d2) : 0.f;
        prior[idx] = (i == j) ? 0.f : 1.f / (1.f + dist);
    } else {
        // W3p[((s*4+nt)*64+l)*8+t] = f16(W3[(128+s*32+(l>>4)*8+t)*64 + nt*16+(l&15)])
        int k = (blk - 1536) * 256 + threadIdx.x;   // 0..8191
        int t = k & 7;
        int l = (k >> 3) & 63;
        int f = k >> 9;
        int s = f >> 2, nt = f & 3;
        int quad = l >> 4, col = l & 15;
        W3ph[k] = (_Float16)W3[(128 + s * 32 + quad * 8 + t) * H_ + nt * 16 + col];
    }
}

// ---------------------------------------------------------------------------
// Kernel 2 (fused): dyn final reduce + node MLP (12->64->64) -> nrh (f16),
// P = r@W3[0:64], Qp = permuted r@W3[64:128]. One 64-thr block per (b,n).
// ---------------------------------------------------------------------------
__global__ __launch_bounds__(64) void node_kernel(
        const float* __restrict__ part, const float* __restrict__ x,
        const float* __restrict__ sc,
        const float* __restrict__ W1, const float* __restrict__ b1,
        const float* __restrict__ W2, const float* __restrict__ b2,
        const float* __restrict__ W3,
        _Float16* __restrict__ nrh, float* __restrict__ P, float* __restrict__ Qp) {
    int blk = blockIdx.x;
    int b = blk >> 9;
    int n = blk & (N_ - 1);
    int o = threadIdx.x;

    __shared__ float f[12];
    __shared__ float h[H_];
    __shared__ float r[H_];

    {
        const int plane = B_ * 32 * N_;
        float Sx = 0.f, Sxx = 0.f, Cnt = 0.f, Ms = 0.f, Bv = 0.f, Bt = -1.f;
        if (o < 32) {
            int base = (b * 32 + o) * N_ + n;
            Sx  = part[0 * plane + base];
            Sxx = part[1 * plane + base];
            Cnt = part[2 * plane + base];
            Ms  = part[3 * plane + base];
            Bv  = part[4 * plane + base];
            Bt  = part[5 * plane + base];
        }
#pragma unroll
        for (int off = 1; off < 32; off <<= 1) {
            Sx  += __shfl_xor(Sx, off);
            Sxx += __shfl_xor(Sxx, off);
            Cnt += __shfl_xor(Cnt, off);
            Ms  += __shfl_xor(Ms, off);
            float obt = __shfl_xor(Bt, off);
            float obv = __shfl_xor(Bv, off);
            if (obt > Bt) { Bt = obt; Bv = obv; }
        }
        if (o == 0) {
            float count = fmaxf(Cnt, 1.f);
            float mean  = Sx / count;
            float var   = (Sxx - 2.f * mean * Sx + mean * mean * Cnt) / count;
            float stdv  = sqrtf(fmaxf(var, 0.f) + 1e-6f);
            float last  = (Bt >= 0.f) ? Bv : x[b * T_ * N_ + n];
            f[0] = mean; f[1] = stdv; f[2] = last; f[3] = Ms * (1.f / (float)T_);
        }
        if (o >= 4 && o < 12) f[o] = sc[n * 8 + (o - 4)];
    }
    __syncthreads();

    float a = b1[o];
#pragma unroll
    for (int k = 0; k < 12; k++) a += f[k] * W1[k * H_ + o];
    h[o] = fmaxf(a, 0.f);
    __syncthreads();

    float a2 = b2[o];
#pragma unroll 8
    for (int k = 0; k < H_; k++) a2 += h[k] * W2[k * H_ + o];
    float rv = fmaxf(a2, 0.f);
    r[o] = rv;
    nrh[(b * N_ + n) * H_ + o] = (_Float16)rv;
    __syncthreads();

    float p = 0.f, q = 0.f;
#pragma unroll 8
    for (int k = 0; k < H_; k++) {
        float rk = r[k];
        p += rk * W3[k * H_ + o];
        q += rk * W3[(H_ + k) * H_ + o];
    }
    P[(b * N_ + n) * H_ + o] = p;
    Qp[(b * N_ + n) * H_ + (o & 15) * 4 + (o >> 4)] = q;
}

// ---------------------------------------------------------------------------
// Kernel 3 (MFMA, packed f16): per (b,i), C[j,o] = [D|M](512x128) @ W3cd(128x64).
// Fragment build in packed f16 (v_pk_add/mul, AND-mask abs): ~24 VALU/iter vs
// ~56 for the bf16 cvt path. Epilogue +P+Qp+b3, relu, dot W4, relu, prior.
// ---------------------------------------------------------------------------
__global__ __launch_bounds__(256) void pair_mfma_kernel(
        const _Float16* __restrict__ nrh, const float* __restrict__ P,
        const float* __restrict__ Qp, const _Float16* __restrict__ W3ph,
        const float* __restrict__ b3, const float* __restrict__ W4,
        const float* __restrict__ b4, const float* __restrict__ prior,
        float* __restrict__ adapt, float* __restrict__ degree) {
    int blk = blockIdx.x;
    int rb = blk >> 9;
    int i = blk & (N_ - 1);
    int tid = threadIdx.x;
    int w = tid >> 6;
    int l = tid & 63;
    int col = l & 15;
    int quad = l >> 4;

    // B fragments: one 16B load each, pre-packed in fragment order
    half8 bf[4][4];
#pragma unroll
    for (int s = 0; s < 4; s++)
#pragma unroll
        for (int nt = 0; nt < 4; nt++)
            bf[s][nt] = *(const half8*)(W3ph + (((s * 4 + nt) * 64 + l) << 3));

    const _Float16* hi_row = nrh + (rb * N_ + i) * H_;
    half8 hiA = *(const half8*)(hi_row + quad * 8);        // k-block 0: k=quad*8+t
    half8 hiB = *(const half8*)(hi_row + 32 + quad * 8);   // k-block 1

    float pb3[4], w4v[4];
#pragma unroll
    for (int nt = 0; nt < 4; nt++) {
        int o = nt * 16 + col;
        pb3[nt] = P[(rb * N_ + i) * H_ + o] + b3[o];
        w4v[nt] = W4[o];
    }
    float b4s = b4[0];
    const float* prow = prior + i * N_;
    const _Float16* nrb = nrh + (rb * N_) * H_;
    float rsum = 0.f;

    // prefetch tile 0
    half8 hA, hB;
    {
        const _Float16* p0 = nrb + (w * 128 + col) * H_;
        hA = *(const half8*)(p0 + quad * 8);
        hB = *(const half8*)(p0 + 32 + quad * 8);
    }

#pragma unroll
    for (int mt = 0; mt < 8; mt++) {
        int j0 = w * 128 + mt * 16;

        // prefetch next hj tile
        half8 nA, nB;
        if (mt < 7) {
            const _Float16* pn = nrb + (j0 + 16 + col) * H_;
            nA = *(const half8*)(pn + quad * 8);
            nB = *(const half8*)(pn + 32 + quad * 8);
        }

        // epilogue operands issued early (hide L2 latency under MFMA)
        floatx4 pv = *(const floatx4*)(prow + j0 + quad * 4);
        floatx4 qv[4];
#pragma unroll
        for (int r = 0; r < 4; r++)
            qv[r] = *(const floatx4*)(Qp + (rb * N_ + j0 + quad * 4 + r) * H_ + col * 4);

        // fragment build: packed f16
        half8 dA = habs8(hiA - hA);
        half8 dB = habs8(hiB - hB);
        half8 mA = hiA * hA;
        half8 mB = hiB * hB;

        floatx4 acc[4];
#pragma unroll
        for (int nt = 0; nt < 4; nt++) acc[nt] = (floatx4){0.f, 0.f, 0.f, 0.f};
#pragma unroll
        for (int nt = 0; nt < 4; nt++) {
            acc[nt] = __builtin_amdgcn_mfma_f32_16x16x32_f16(dA, bf[0][nt], acc[nt], 0, 0, 0);
            acc[nt] = __builtin_amdgcn_mfma_f32_16x16x32_f16(dB, bf[1][nt], acc[nt], 0, 0, 0);
            acc[nt] = __builtin_amdgcn_mfma_f32_16x16x32_f16(mA, bf[2][nt], acc[nt], 0, 0, 0);
            acc[nt] = __builtin_amdgcn_mfma_f32_16x16x32_f16(mB, bf[3][nt], acc[nt], 0, 0, 0);
        }

        float ed[4];
#pragma unroll
        for (int r = 0; r < 4; r++) {
            int j = j0 + quad * 4 + r;
            float p = 0.f;
#pragma unroll
            for (int nt = 0; nt < 4; nt++)
                p += fmaxf(acc[nt][r] + pb3[nt] + qv[r][nt], 0.f) * w4v[nt];
            p += __shfl_xor(p, 1);
            p += __shfl_xor(p, 2);
            p += __shfl_xor(p, 4);
            p += __shfl_xor(p, 8);
            float edge = fmaxf(p + b4s, 0.f);
            float ad = (j == i) ? 1.0f : edge * pv[r];
            ed[r] = ad;
            rsum += ad;
        }
        if (col == 0) {
            *(floatx4*)&adapt[(size_t)(rb * N_ + i) * N_ + j0 + quad * 4] =
                (floatx4){ed[0], ed[1], ed[2], ed[3]};
        }
        if (mt < 7) { hA = nA; hB = nB; }
    }

    rsum += __shfl_xor(rsum, 16);
    rsum += __shfl_xor(rsum, 32);
    __shared__ float sRow[4];
    if (l == 0) sRow[w] = rsum;
    __syncthreads();
    if (tid == 0) degree[rb * N_ + i] = sRow[0] + sRow[1] + sRow[2] + sRow[3];
}

// ---------------------------------------------------------------------------
// Kernel 4: symmetric normalization out = D^-1/2 A D^-1/2 (float4)
// ---------------------------------------------------------------------------
__global__ void norm_kernel(const float* __restrict__ adapt, const float* __restrict__ deg,
                            float* __restrict__ out) {
    int idx = blockIdx.x * 256 + threadIdx.x;      // one float4 each
    int b = idx >> 16;
    int r = (idx >> 7) & (N_ - 1);
    int c4 = (idx & 127) << 2;
    float dr = rsqrtf(fmaxf(deg[b * N_ + r], 1e-6f));
    floatx4 a = *(const floatx4*)(adapt + ((size_t)idx << 2));
    floatx4 o;
#pragma unroll
    for (int k = 0; k < 4; k++)
        o[k] = dr * a[k] * rsqrtf(fmaxf(deg[b * N_ + c4 + k], 1e-6f));
    *(floatx4*)(out + ((size_t)idx << 2)) = o;
}

extern "C" void kernel_launch(void* const* d_in, const int* in_sizes, int n_in,
                              void* d_out, int out_size, void* d_ws, size_t ws_size,
                              hipStream_t stream) {
    const float* x      = (const float*)d_in[0];
    const float* mask   = (const float*)d_in[1];
    const float* sc     = (const float*)d_in[2];
    const float* coords = (const float*)d_in[3];
    const float* W1 = (const float*)d_in[4];
    const float* b1 = (const float*)d_in[5];
    const float* W2 = (const float*)d_in[6];
    const float* b2 = (const float*)d_in[7];
    const float* W3 = (const float*)d_in[8];
    const float* b3 = (const float*)d_in[9];
    const float* W4 = (const float*)d_in[10];
    const float* b4 = (const float*)d_in[11];
    float* out = (float*)d_out;

    float* wsp = (float*)d_ws;
    float* P       = wsp;                            // 65536 floats
    float* Qp      = wsp + 65536;                    // 65536
    float* prior   = wsp + 131072;                   // 262144
    _Float16* nrh  = (_Float16*)(wsp + 393216);      // 65536 halves (32768 floats)
    _Float16* W3ph = (_Float16*)(wsp + 425984);      // 8192 halves (4096 floats)
    float* deg     = wsp + 430080;                   // 1024
    float* adapt   = wsp + 431104;                   // 524288; dyn partials overlay
    float* part    = adapt;                          // 196608 <= 524288

    prep_kernel<<<1568, 256, 0, stream>>>(x, mask, coords, W3, part, prior, W3ph);
    node_kernel<<<B_ * N_, 64, 0, stream>>>(part, x, sc, W1, b1, W2, b2, W3, nrh, P, Qp);
    pair_mfma_kernel<<<B_ * N_, 256, 0, stream>>>(nrh, P, Qp, W3ph, b3, W4, b4, prior, adapt, deg);
    norm_kernel<<<512, 256, 0, stream>>>(adapt, deg, out);
}